// Round 10
// baseline (154.072 us; speedup 1.0000x reference)
//
#include <hip/hip_runtime.h>

#define NN  10000
#define NE  640000
#define IC  512
#define H   7
#define HP  8                      // padded g row stride (2x float4)
#define NCH 256                    // K0 bucket chunks
#define CE  (NE / NCH)             // 2500 edges per chunk
#define RG  250                    // row ranges (buckets)
#define RN  40                     // nodes per range
#define CAP 3072                   // bucket capacity (mean 2560, max~2740)

// WORK-DOUBLING PROBE: each kernel's main loop runs twice (idempotent);
// dispatch count unchanged. Separates fixed per-dispatch overhead from
// real kernel work. Outputs identical to R9.

__device__ __forceinline__ float wave_sum(float v) {
    #pragma unroll
    for (int off = 32; off; off >>= 1) v += __shfl_xor(v, off);
    return v;
}

__global__ __launch_bounds__(1024) void k_bucket(
    const int* __restrict__ row, const int* __restrict__ col,
    const float* __restrict__ ew, int* __restrict__ gcur,
    int2* __restrict__ gbuf)
{
    __shared__ int   lhist[RG];
    __shared__ int   loffs[RG];
    __shared__ int   lbase[RG];
    __shared__ int   lcur[RG];
    __shared__ int2  st[CE];
    __shared__ unsigned short strg[CE];
    const int tid = threadIdx.x;
    const int base = blockIdx.x * CE;
    int er[3]; float ef[3]; int erg[3];
    for (int it = 0; it < 2; ++it) {
        if (tid < RG) lhist[tid] = 0;
        __syncthreads();
        #pragma unroll
        for (int k = 0; k < 3; ++k) {
            const int i = tid + k * 1024;
            er[k] = -1;
            if (i < CE) {
                const int e = base + i;
                const int r = row[e], c = col[e];
                const int rg = r / RN, rl = r - rg * RN;
                er[k] = c | (rl << 14);
                ef[k] = ew[e];
                erg[k] = rg;
                atomicAdd(&lhist[rg], 1);
            }
        }
        __syncthreads();
        if (it == 1 && tid < RG)
            lbase[tid] = tid * CAP + atomicAdd(&gcur[tid], lhist[tid]);
        if (tid < 64) {                  // exclusive scan of lhist (wave 0)
            const int ln = tid;
            int t4[4]; int s4 = 0;
            #pragma unroll
            for (int k = 0; k < 4; ++k) {
                const int j = ln * 4 + k;
                t4[k] = (j < RG) ? lhist[j] : 0;
                s4 += t4[k];
            }
            int s = s4;
            #pragma unroll
            for (int off = 1; off < 64; off <<= 1) {
                const int t = __shfl_up(s, off);
                if (ln >= off) s += t;
            }
            int run = s - s4;
            #pragma unroll
            for (int k = 0; k < 4; ++k) {
                const int j = ln * 4 + k;
                if (j < RG) { loffs[j] = run; lcur[j] = run; }
                run += t4[k];
            }
        }
        __syncthreads();
        #pragma unroll
        for (int k = 0; k < 3; ++k) {
            if (er[k] >= 0) {
                const int pos = atomicAdd(&lcur[erg[k]], 1);
                st[pos] = make_int2(er[k], __float_as_int(ef[k]));
                strg[pos] = (unsigned short)erg[k];
            }
        }
        __syncthreads();
    }
    #pragma unroll
    for (int k = 0; k < 3; ++k) {
        const int i = tid + k * 1024;
        if (i < CE) {
            const int rg = strg[i];
            gbuf[lbase[rg] + (i - loffs[rg])] = st[i];
        }
    }
}

__global__ __launch_bounds__(512) void k_deg_mm1(
    const int* __restrict__ gcur, const int2* __restrict__ gbuf,
    const float* __restrict__ x, const float* __restrict__ W1,
    float* __restrict__ dinv, float* __restrict__ g1)
{
    __shared__ float wls[IC * H];
    __shared__ float ldeg[RN];
    __shared__ float ldv[RN];
    __shared__ float htile[RN][HP];
    const int tid = threadIdx.x, b = blockIdx.x;
    const int wv = tid >> 6, ln = tid & 63;
    if (tid < RN) htile[tid][7] = 0.0f;
    for (int i = tid; i < IC * H; i += 512) wls[i] = W1[i];
    const int cnt = gcur[b];
    const int2* bk = gbuf + (size_t)b * CAP;
    for (int it = 0; it < 2; ++it) {
        if (tid < RN) ldeg[tid] = 0.0f;
        __syncthreads();
        for (int i = tid; i < cnt; i += 512) {
            const int2 e = bk[i];
            atomicAdd(&ldeg[e.x >> 14], __int_as_float(e.y));
        }
        __syncthreads();
        if (tid < RN) {
            const float d = rsqrtf(1.0f + ldeg[tid]);
            ldv[tid] = d;
            if (it == 1) dinv[b * RN + tid] = d;
        }
        for (int q = 0; q < 5; ++q) {
            const int rl = wv * 5 + q;
            const float4* xr4 = (const float4*)(x + (size_t)(b * RN + rl) * IC);
            const float4 a0 = xr4[ln * 2], a1 = xr4[ln * 2 + 1];
            const float e8[8] = {a0.x, a0.y, a0.z, a0.w, a1.x, a1.y, a1.z, a1.w};
            const float* wb = &wls[ln * 8 * H];
            float acc[H] = {};
            #pragma unroll
            for (int m = 0; m < 8; ++m)
                #pragma unroll
                for (int c = 0; c < H; ++c) acc[c] += e8[m] * wb[m * H + c];
            #pragma unroll
            for (int c = 0; c < H; ++c) {
                const float v = wave_sum(acc[c]);
                if (ln == 0) htile[rl][c] = v;
            }
        }
        __syncthreads();
    }
    if (tid < RN * HP) {
        const int n = tid >> 3, j = tid & 7;
        g1[(size_t)(b * RN) * HP + tid] = ldv[n] * htile[n][j];
    }
}

__global__ __launch_bounds__(512) void k_gather1(
    const int* __restrict__ gcur, const int2* __restrict__ gbuf,
    const float* __restrict__ dinv, const float* __restrict__ g1,
    const float* __restrict__ b1, const float* __restrict__ W2,
    float* __restrict__ g2)
{
    __shared__ float acc[RN][9];
    __shared__ float vv[RN][HP];
    __shared__ float ldv[RN];
    __shared__ float w2[H * H];
    __shared__ float bb[H];
    const int tid = threadIdx.x, b = blockIdx.x;
    if (tid >= 384 && tid < 384 + H * H) w2[tid - 384] = W2[tid - 384];
    if (tid >= 448 && tid < 448 + H) bb[tid - 448] = b1[tid - 448];
    if (tid >= 456 && tid < 456 + RN) ldv[tid - 456] = dinv[b * RN + tid - 456];
    const int cnt = gcur[b];
    const int2* bk = gbuf + (size_t)b * CAP;
    for (int it = 0; it < 2; ++it) {
        if (tid < RN * 9) ((float*)acc)[tid] = 0.0f;
        __syncthreads();
        for (int i = tid; i < cnt; i += 512) {
            const int2 e = bk[i];
            const int c = e.x & 16383, rl = e.x >> 14;
            const float w = __int_as_float(e.y);
            const float4* gc = (const float4*)(g1 + (size_t)c * HP);
            const float4 lo = gc[0], hi = gc[1];
            atomicAdd(&acc[rl][0], w * lo.x);
            atomicAdd(&acc[rl][1], w * lo.y);
            atomicAdd(&acc[rl][2], w * lo.z);
            atomicAdd(&acc[rl][3], w * lo.w);
            atomicAdd(&acc[rl][4], w * hi.x);
            atomicAdd(&acc[rl][5], w * hi.y);
            atomicAdd(&acc[rl][6], w * hi.z);
        }
        __syncthreads();
    }
    if (tid < RN * H) {
        const int n = tid / H, k = tid - n * H;
        const int gn = b * RN + n;
        const float di = ldv[n];
        vv[n][k] = di * (acc[n][k] + g1[(size_t)gn * HP + k]) + bb[k];
    }
    __syncthreads();
    if (tid < RN * H) {
        const int n = tid / H, k = tid - n * H;
        const int gn = b * RN + n;
        float o = 0.0f;
        #pragma unroll
        for (int j = 0; j < H; ++j) o += vv[n][j] * w2[j * H + k];
        g2[(size_t)gn * HP + k] = ldv[n] * o;
    }
    if (tid >= 448 && tid < 448 + RN)
        g2[(size_t)(b * RN + tid - 448) * HP + 7] = 0.0f;
}

__global__ __launch_bounds__(512) void k_gather2(
    const int* __restrict__ gcur, const int2* __restrict__ gbuf,
    const float* __restrict__ dinv, const float* __restrict__ g2,
    const float* __restrict__ b2, float* __restrict__ dout)
{
    __shared__ float acc[RN][9];
    __shared__ float ldv[RN];
    __shared__ float bb[H];
    const int tid = threadIdx.x, b = blockIdx.x;
    if (b == 0 && tid == 511) dout[(size_t)NN * H] = 0.0f;   // reg
    if (tid >= 448 && tid < 448 + H) bb[tid - 448] = b2[tid - 448];
    if (tid >= 456 && tid < 456 + RN) ldv[tid - 456] = dinv[b * RN + tid - 456];
    const int cnt = gcur[b];
    const int2* bk = gbuf + (size_t)b * CAP;
    for (int it = 0; it < 2; ++it) {
        if (tid < RN * 9) ((float*)acc)[tid] = 0.0f;
        __syncthreads();
        for (int i = tid; i < cnt; i += 512) {
            const int2 e = bk[i];
            const int c = e.x & 16383, rl = e.x >> 14;
            const float w = __int_as_float(e.y);
            const float4* gc = (const float4*)(g2 + (size_t)c * HP);
            const float4 lo = gc[0], hi = gc[1];
            atomicAdd(&acc[rl][0], w * lo.x);
            atomicAdd(&acc[rl][1], w * lo.y);
            atomicAdd(&acc[rl][2], w * lo.z);
            atomicAdd(&acc[rl][3], w * lo.w);
            atomicAdd(&acc[rl][4], w * hi.x);
            atomicAdd(&acc[rl][5], w * hi.y);
            atomicAdd(&acc[rl][6], w * hi.z);
        }
        __syncthreads();
    }
    if (tid < RN * H) {
        const int n = tid / H, k = tid - n * H;
        const int gn = b * RN + n;
        const float di = ldv[n];
        dout[(size_t)gn * H + k] = di * (acc[n][k] + g2[(size_t)gn * HP + k]) + bb[k];
    }
}

extern "C" void kernel_launch(void* const* d_in, const int* in_sizes, int n_in,
                              void* d_out, int out_size, void* d_ws, size_t ws_size,
                              hipStream_t stream) {
    const float* x  = (const float*)d_in[0];
    const int*   ei = (const int*)d_in[1];
    const float* ea = (const float*)d_in[2];
    const float* W1 = (const float*)d_in[4];
    const float* b1 = (const float*)d_in[5];
    const float* W2 = (const float*)d_in[6];
    const float* b2 = (const float*)d_in[7];
    float* out = (float*)d_out;

    char* p = (char*)d_ws;
    int* gcur = (int*)p;          p += 1024;
    int2* gbuf = (int2*)p;        p += sizeof(int2) * RG * CAP;    // 6.1 MB
    float* g1 = (float*)p;        p += sizeof(float) * NN * HP;
    float* g2 = (float*)p;        p += sizeof(float) * NN * HP;
    float* dinv = (float*)p;      p += sizeof(float) * NN;

    const int* row = ei;
    const int* col = ei + NE;

    hipMemsetAsync(gcur, 0, RG * sizeof(int), stream);
    k_bucket<<<NCH, 1024, 0, stream>>>(row, col, ea, gcur, gbuf);
    k_deg_mm1<<<RG, 512, 0, stream>>>(gcur, gbuf, x, W1, dinv, g1);
    k_gather1<<<RG, 512, 0, stream>>>(gcur, gbuf, dinv, g1, b1, W2, g2);
    k_gather2<<<RG, 512, 0, stream>>>(gcur, gbuf, dinv, g2, b2, out);
}

// Round 11
// 102.327 us; speedup vs baseline: 1.5057x; 1.5057x over previous
//
#include <hip/hip_runtime.h>

#define NN  10000
#define NE  640000
#define IC  512
#define H   7
#define HP  8                      // padded h/g row stride (2x float4)
#define NCH 256                    // bucket chunks
#define CE  (NE / NCH)             // 2500 edges per chunk
#define RG  250                    // row ranges (buckets)
#define RN  40                     // nodes per range
#define CAP 3072                   // bucket capacity (mean 2560, max~2740)
#define MMB 625                    // mm1 blocks (16 rows each)

__device__ __forceinline__ float wave_sum(float v) {
    #pragma unroll
    for (int off = 32; off; off >>= 1) v += __shfl_xor(v, off);
    return v;
}

// K0: blocks [0,NCH) bucket edges by row-range (LDS counting sort, rg packed
// in bits 20-27, coalesced write-out); blocks [NCH,NCH+MMB) do mm1 rows.
__global__ __launch_bounds__(1024) void k_bucket_mm1(
    const int* __restrict__ row, const int* __restrict__ col,
    const float* __restrict__ ew, const float* __restrict__ x,
    const float* __restrict__ W1, int* __restrict__ gcur,
    int2* __restrict__ gbuf, float* __restrict__ h1)
{
    __shared__ int   lhist[RG];
    __shared__ int   loffs[RG];
    __shared__ int   lbase[RG];
    __shared__ int   lcur[RG];
    __shared__ int2  st[CE];            // 20 KB
    __shared__ float wls[IC * H];       // 14 KB (mm1 branch)
    const int tid = threadIdx.x;

    if (blockIdx.x < NCH) {
        const int base = blockIdx.x * CE;
        if (tid < RG) lhist[tid] = 0;
        __syncthreads();
        int ex[3]; float ef[3];
        #pragma unroll
        for (int k = 0; k < 3; ++k) {
            const int i = tid + k * 1024;
            ex[k] = -1;
            if (i < CE) {
                const int e = base + i;
                const int r = row[e], c = col[e];
                const int rg = r / RN, rl = r - rg * RN;
                ex[k] = c | (rl << 14) | (rg << 20);    // 14+6+8 bits
                ef[k] = ew[e];
                atomicAdd(&lhist[rg], 1);
            }
        }
        __syncthreads();
        if (tid < RG) lbase[tid] = tid * CAP + atomicAdd(&gcur[tid], lhist[tid]);
        if (tid < 64) {                  // exclusive scan of lhist (wave 0)
            const int ln = tid;
            int t4[4]; int s4 = 0;
            #pragma unroll
            for (int k = 0; k < 4; ++k) {
                const int j = ln * 4 + k;
                t4[k] = (j < RG) ? lhist[j] : 0;
                s4 += t4[k];
            }
            int s = s4;
            #pragma unroll
            for (int off = 1; off < 64; off <<= 1) {
                const int t = __shfl_up(s, off);
                if (ln >= off) s += t;
            }
            int run = s - s4;
            #pragma unroll
            for (int k = 0; k < 4; ++k) {
                const int j = ln * 4 + k;
                if (j < RG) { loffs[j] = run; lcur[j] = run; }
                run += t4[k];
            }
        }
        __syncthreads();
        #pragma unroll
        for (int k = 0; k < 3; ++k) {
            if (ex[k] >= 0) {
                const int pos = atomicAdd(&lcur[ex[k] >> 20], 1);
                st[pos] = make_int2(ex[k], __float_as_int(ef[k]));
            }
        }
        __syncthreads();
        #pragma unroll
        for (int k = 0; k < 3; ++k) {
            const int i = tid + k * 1024;
            if (i < CE) {
                const int rg = st[i].x >> 20;
                gbuf[lbase[rg] + (i - loffs[rg])] = st[i];
            }
        }
    } else {
        for (int i = tid; i < IC * H; i += 1024) wls[i] = W1[i];
        __syncthreads();
        const int wv = tid >> 6, ln = tid & 63;
        const int r = (blockIdx.x - NCH) * 16 + wv;     // one row per wave
        const float4* xr4 = (const float4*)(x + (size_t)r * IC);
        const float4 a0 = xr4[ln * 2], a1 = xr4[ln * 2 + 1];
        const float e8[8] = {a0.x, a0.y, a0.z, a0.w, a1.x, a1.y, a1.z, a1.w};
        const float* wb = &wls[ln * 8 * H];
        float acc[H] = {};
        #pragma unroll
        for (int m = 0; m < 8; ++m)
            #pragma unroll
            for (int c = 0; c < H; ++c) acc[c] += e8[m] * wb[m * H + c];
        #pragma unroll
        for (int c = 0; c < H; ++c) {
            const float v = wave_sum(acc[c]);
            if (ln == 0) h1[r * HP + c] = v;
        }
        if (ln == 0) h1[r * HP + 7] = 0.0f;
    }
}

// K1: per-range deg (prefetch-unrolled pass over own bucket) -> dinv;
// g1 = dinv * h1.
__global__ __launch_bounds__(1024) void k_deg_g1(
    const int* __restrict__ gcur, const int2* __restrict__ gbuf,
    const float* __restrict__ h1, float* __restrict__ dinv,
    float* __restrict__ g1)
{
    __shared__ float ldeg[RN];
    __shared__ float ldv[RN];
    const int tid = threadIdx.x, b = blockIdx.x;
    if (tid < RN) ldeg[tid] = 0.0f;
    __syncthreads();
    const int cnt = gcur[b];
    const int2* bk = gbuf + (size_t)b * CAP;
    {
        const int i0 = tid, i1 = tid + 1024, i2 = tid + 2048;
        const int2 e0 = bk[i0 < cnt ? i0 : 0];
        const int2 e1 = bk[i1 < cnt ? i1 : 0];
        const int2 e2 = bk[i2 < cnt ? i2 : 0];
        const float w0 = i0 < cnt ? __int_as_float(e0.y) : 0.0f;
        const float w1 = i1 < cnt ? __int_as_float(e1.y) : 0.0f;
        const float w2 = i2 < cnt ? __int_as_float(e2.y) : 0.0f;
        atomicAdd(&ldeg[(e0.x >> 14) & 63], w0);
        atomicAdd(&ldeg[(e1.x >> 14) & 63], w1);
        atomicAdd(&ldeg[(e2.x >> 14) & 63], w2);
    }
    __syncthreads();
    if (tid < RN) {
        const float d = rsqrtf(1.0f + ldeg[tid]);
        ldv[tid] = d;
        dinv[b * RN + tid] = d;
    }
    __syncthreads();
    if (tid < RN * HP) {
        const int n = tid >> 3;
        g1[(size_t)(b * RN) * HP + tid] = ldv[n] * h1[(size_t)(b * RN) * HP + tid];
    }
}

// K2: gather layer 1 + bias + mm2 -> g2 = dinv*(out1 @ W2).
__global__ __launch_bounds__(1024) void k_gather1(
    const int* __restrict__ gcur, const int2* __restrict__ gbuf,
    const float* __restrict__ dinv, const float* __restrict__ g1,
    const float* __restrict__ b1, const float* __restrict__ W2,
    float* __restrict__ g2)
{
    __shared__ float acc[RN][9];        // stride 9 (coprime banks)
    __shared__ float vv[RN][H];
    __shared__ float ldv[RN];
    __shared__ float w2[H * H];
    __shared__ float bb[H];
    const int tid = threadIdx.x, b = blockIdx.x;
    if (tid < RN * 9) ((float*)acc)[tid] = 0.0f;
    if (tid >= 512 && tid < 512 + H * H) w2[tid - 512] = W2[tid - 512];
    if (tid >= 576 && tid < 576 + H) bb[tid - 576] = b1[tid - 576];
    if (tid >= 640 && tid < 640 + RN) ldv[tid - 640] = dinv[b * RN + tid - 640];
    __syncthreads();
    const int cnt = gcur[b];
    const int2* bk = gbuf + (size_t)b * CAP;
    {
        const int i0 = tid, i1 = tid + 1024, i2 = tid + 2048;
        const int2 e0 = bk[i0 < cnt ? i0 : 0];
        const int2 e1 = bk[i1 < cnt ? i1 : 0];
        const int2 e2 = bk[i2 < cnt ? i2 : 0];
        const float4* p0 = (const float4*)(g1 + (size_t)(e0.x & 16383) * HP);
        const float4* p1 = (const float4*)(g1 + (size_t)(e1.x & 16383) * HP);
        const float4* p2 = (const float4*)(g1 + (size_t)(e2.x & 16383) * HP);
        const float4 lo0 = p0[0], hi0 = p0[1];
        const float4 lo1 = p1[0], hi1 = p1[1];
        const float4 lo2 = p2[0], hi2 = p2[1];
        const float w0 = i0 < cnt ? __int_as_float(e0.y) : 0.0f;
        const float w1 = i1 < cnt ? __int_as_float(e1.y) : 0.0f;
        const float w2_ = i2 < cnt ? __int_as_float(e2.y) : 0.0f;
        const int r0 = (e0.x >> 14) & 63, r1 = (e1.x >> 14) & 63, r2 = (e2.x >> 14) & 63;
        atomicAdd(&acc[r0][0], w0 * lo0.x); atomicAdd(&acc[r0][1], w0 * lo0.y);
        atomicAdd(&acc[r0][2], w0 * lo0.z); atomicAdd(&acc[r0][3], w0 * lo0.w);
        atomicAdd(&acc[r0][4], w0 * hi0.x); atomicAdd(&acc[r0][5], w0 * hi0.y);
        atomicAdd(&acc[r0][6], w0 * hi0.z);
        atomicAdd(&acc[r1][0], w1 * lo1.x); atomicAdd(&acc[r1][1], w1 * lo1.y);
        atomicAdd(&acc[r1][2], w1 * lo1.z); atomicAdd(&acc[r1][3], w1 * lo1.w);
        atomicAdd(&acc[r1][4], w1 * hi1.x); atomicAdd(&acc[r1][5], w1 * hi1.y);
        atomicAdd(&acc[r1][6], w1 * hi1.z);
        atomicAdd(&acc[r2][0], w2_ * lo2.x); atomicAdd(&acc[r2][1], w2_ * lo2.y);
        atomicAdd(&acc[r2][2], w2_ * lo2.z); atomicAdd(&acc[r2][3], w2_ * lo2.w);
        atomicAdd(&acc[r2][4], w2_ * hi2.x); atomicAdd(&acc[r2][5], w2_ * hi2.y);
        atomicAdd(&acc[r2][6], w2_ * hi2.z);
    }
    __syncthreads();
    if (tid < RN * H) {
        const int n = tid / H, k = tid - n * H;
        const int gn = b * RN + n;
        vv[n][k] = ldv[n] * (acc[n][k] + g1[(size_t)gn * HP + k]) + bb[k];
    }
    __syncthreads();
    if (tid < RN * H) {
        const int n = tid / H, k = tid - n * H;
        const int gn = b * RN + n;
        float o = 0.0f;
        #pragma unroll
        for (int j = 0; j < H; ++j) o += vv[n][j] * w2[j * H + k];
        g2[(size_t)gn * HP + k] = ldv[n] * o;
    }
    if (tid >= 768 && tid < 768 + RN)
        g2[(size_t)(b * RN + tid - 768) * HP + 7] = 0.0f;
}

// K3: gather layer 2 + bias -> dout (stride 7) + reg element.
__global__ __launch_bounds__(1024) void k_gather2(
    const int* __restrict__ gcur, const int2* __restrict__ gbuf,
    const float* __restrict__ dinv, const float* __restrict__ g2,
    const float* __restrict__ b2, float* __restrict__ dout)
{
    __shared__ float acc[RN][9];
    __shared__ float ldv[RN];
    __shared__ float bb[H];
    const int tid = threadIdx.x, b = blockIdx.x;
    if (b == 0 && tid == 1023) dout[(size_t)NN * H] = 0.0f;   // reg
    if (tid < RN * 9) ((float*)acc)[tid] = 0.0f;
    if (tid >= 576 && tid < 576 + H) bb[tid - 576] = b2[tid - 576];
    if (tid >= 640 && tid < 640 + RN) ldv[tid - 640] = dinv[b * RN + tid - 640];
    __syncthreads();
    const int cnt = gcur[b];
    const int2* bk = gbuf + (size_t)b * CAP;
    {
        const int i0 = tid, i1 = tid + 1024, i2 = tid + 2048;
        const int2 e0 = bk[i0 < cnt ? i0 : 0];
        const int2 e1 = bk[i1 < cnt ? i1 : 0];
        const int2 e2 = bk[i2 < cnt ? i2 : 0];
        const float4* p0 = (const float4*)(g2 + (size_t)(e0.x & 16383) * HP);
        const float4* p1 = (const float4*)(g2 + (size_t)(e1.x & 16383) * HP);
        const float4* p2 = (const float4*)(g2 + (size_t)(e2.x & 16383) * HP);
        const float4 lo0 = p0[0], hi0 = p0[1];
        const float4 lo1 = p1[0], hi1 = p1[1];
        const float4 lo2 = p2[0], hi2 = p2[1];
        const float w0 = i0 < cnt ? __int_as_float(e0.y) : 0.0f;
        const float w1 = i1 < cnt ? __int_as_float(e1.y) : 0.0f;
        const float w2_ = i2 < cnt ? __int_as_float(e2.y) : 0.0f;
        const int r0 = (e0.x >> 14) & 63, r1 = (e1.x >> 14) & 63, r2 = (e2.x >> 14) & 63;
        atomicAdd(&acc[r0][0], w0 * lo0.x); atomicAdd(&acc[r0][1], w0 * lo0.y);
        atomicAdd(&acc[r0][2], w0 * lo0.z); atomicAdd(&acc[r0][3], w0 * lo0.w);
        atomicAdd(&acc[r0][4], w0 * hi0.x); atomicAdd(&acc[r0][5], w0 * hi0.y);
        atomicAdd(&acc[r0][6], w0 * hi0.z);
        atomicAdd(&acc[r1][0], w1 * lo1.x); atomicAdd(&acc[r1][1], w1 * lo1.y);
        atomicAdd(&acc[r1][2], w1 * lo1.z); atomicAdd(&acc[r1][3], w1 * lo1.w);
        atomicAdd(&acc[r1][4], w1 * hi1.x); atomicAdd(&acc[r1][5], w1 * hi1.y);
        atomicAdd(&acc[r1][6], w1 * hi1.z);
        atomicAdd(&acc[r2][0], w2_ * lo2.x); atomicAdd(&acc[r2][1], w2_ * lo2.y);
        atomicAdd(&acc[r2][2], w2_ * lo2.z); atomicAdd(&acc[r2][3], w2_ * lo2.w);
        atomicAdd(&acc[r2][4], w2_ * hi2.x); atomicAdd(&acc[r2][5], w2_ * hi2.y);
        atomicAdd(&acc[r2][6], w2_ * hi2.z);
    }
    __syncthreads();
    if (tid < RN * H) {
        const int n = tid / H, k = tid - n * H;
        const int gn = b * RN + n;
        dout[(size_t)gn * H + k] =
            ldv[n] * (acc[n][k] + g2[(size_t)gn * HP + k]) + bb[k];
    }
}

extern "C" void kernel_launch(void* const* d_in, const int* in_sizes, int n_in,
                              void* d_out, int out_size, void* d_ws, size_t ws_size,
                              hipStream_t stream) {
    const float* x  = (const float*)d_in[0];
    const int*   ei = (const int*)d_in[1];
    const float* ea = (const float*)d_in[2];
    const float* W1 = (const float*)d_in[4];
    const float* b1 = (const float*)d_in[5];
    const float* W2 = (const float*)d_in[6];
    const float* b2 = (const float*)d_in[7];
    float* out = (float*)d_out;

    char* p = (char*)d_ws;
    int* gcur = (int*)p;          p += 1024;
    int2* gbuf = (int2*)p;        p += sizeof(int2) * RG * CAP;    // 6.1 MB
    float* h1 = (float*)p;        p += sizeof(float) * NN * HP;
    float* g1 = (float*)p;        p += sizeof(float) * NN * HP;
    float* g2 = (float*)p;        p += sizeof(float) * NN * HP;
    float* dinv = (float*)p;      p += sizeof(float) * NN;

    const int* row = ei;
    const int* col = ei + NE;

    hipMemsetAsync(gcur, 0, RG * sizeof(int), stream);
    k_bucket_mm1<<<NCH + MMB, 1024, 0, stream>>>(row, col, ea, x, W1, gcur, gbuf, h1);
    k_deg_g1<<<RG, 1024, 0, stream>>>(gcur, gbuf, h1, dinv, g1);
    k_gather1<<<RG, 1024, 0, stream>>>(gcur, gbuf, dinv, g1, b1, W2, g2);
    k_gather2<<<RG, 1024, 0, stream>>>(gcur, gbuf, dinv, g2, b2, out);
}

// Round 12
// 59.670 us; speedup vs baseline: 2.5821x; 1.7149x over previous
//
#include <hip/hip_runtime.h>

#define NN   10000
#define NE   640000
#define IC   512
#define H    7
#define HP   8                     // padded h/g row stride (2x float4)
#define NCH  256                   // bucket chunks
#define CE   (NE / NCH)            // 2500 edges per chunk
#define RG   250                   // row ranges (buckets)
#define RN   40                    // nodes per range
#define CAP  3072                  // bucket capacity (mean 2560, max~2740)
#define MMB  625                   // mm1 blocks (16 rows each)
#define NSPB 20                    // nodes per gather block
#define NGB  (NN / NSPB)           // 500 gather blocks

__device__ __forceinline__ float wave_sum(float v) {
    #pragma unroll
    for (int off = 32; off; off >>= 1) v += __shfl_xor(v, off);
    return v;
}

// K0: blocks [0,NCH) bucket edges by row-range (LDS counting sort by rg,
// one global cursor atomic per range, coalesced write-out of
// {col | rl<<14 | rg<<20, ew}); blocks [NCH,NCH+MMB) compute mm1 rows.
__global__ __launch_bounds__(1024) void k_bucket_mm1(
    const int* __restrict__ row, const int* __restrict__ col,
    const float* __restrict__ ew, const float* __restrict__ x,
    const float* __restrict__ W1, int* __restrict__ gcur,
    int2* __restrict__ gbuf, float* __restrict__ h1)
{
    __shared__ int   lhist[RG];
    __shared__ int   loffs[RG];
    __shared__ int   lbase[RG];
    __shared__ int   lcur[RG];
    __shared__ int2  st[CE];            // 20 KB
    __shared__ float wls[IC * H];       // 14 KB (mm1 branch)
    const int tid = threadIdx.x;

    if (blockIdx.x < NCH) {
        const int base = blockIdx.x * CE;
        if (tid < RG) lhist[tid] = 0;
        __syncthreads();
        int ex[3]; float ef[3];
        #pragma unroll
        for (int k = 0; k < 3; ++k) {
            const int i = tid + k * 1024;
            ex[k] = -1;
            if (i < CE) {
                const int e = base + i;
                const int r = row[e], c = col[e];
                const int rg = r / RN, rl = r - rg * RN;
                ex[k] = c | (rl << 14) | (rg << 20);
                ef[k] = ew[e];
                atomicAdd(&lhist[rg], 1);
            }
        }
        __syncthreads();
        if (tid < RG) lbase[tid] = tid * CAP + atomicAdd(&gcur[tid], lhist[tid]);
        if (tid < 64) {                  // exclusive scan of lhist (wave 0)
            const int ln = tid;
            int t4[4]; int s4 = 0;
            #pragma unroll
            for (int k = 0; k < 4; ++k) {
                const int j = ln * 4 + k;
                t4[k] = (j < RG) ? lhist[j] : 0;
                s4 += t4[k];
            }
            int s = s4;
            #pragma unroll
            for (int off = 1; off < 64; off <<= 1) {
                const int t = __shfl_up(s, off);
                if (ln >= off) s += t;
            }
            int run = s - s4;
            #pragma unroll
            for (int k = 0; k < 4; ++k) {
                const int j = ln * 4 + k;
                if (j < RG) { loffs[j] = run; lcur[j] = run; }
                run += t4[k];
            }
        }
        __syncthreads();
        #pragma unroll
        for (int k = 0; k < 3; ++k) {
            if (ex[k] >= 0) {
                const int pos = atomicAdd(&lcur[ex[k] >> 20], 1);
                st[pos] = make_int2(ex[k], __float_as_int(ef[k]));
            }
        }
        __syncthreads();
        #pragma unroll
        for (int k = 0; k < 3; ++k) {
            const int i = tid + k * 1024;
            if (i < CE) {
                const int rg = st[i].x >> 20;
                gbuf[lbase[rg] + (i - loffs[rg])] = st[i];
            }
        }
    } else {
        for (int i = tid; i < IC * H; i += 1024) wls[i] = W1[i];
        __syncthreads();
        const int wv = tid >> 6, ln = tid & 63;
        const int r = (blockIdx.x - NCH) * 16 + wv;     // one row per wave
        const float4* xr4 = (const float4*)(x + (size_t)r * IC);
        const float4 a0 = xr4[ln * 2], a1 = xr4[ln * 2 + 1];
        const float e8[8] = {a0.x, a0.y, a0.z, a0.w, a1.x, a1.y, a1.z, a1.w};
        const float* wb = &wls[ln * 8 * H];
        float acc[H] = {};
        #pragma unroll
        for (int m = 0; m < 8; ++m)
            #pragma unroll
            for (int c = 0; c < H; ++c) acc[c] += e8[m] * wb[m * H + c];
        #pragma unroll
        for (int c = 0; c < H; ++c) {
            const float v = wave_sum(acc[c]);
            if (ln == 0) h1[r * HP + c] = v;
        }
        if (ln == 0) h1[r * HP + 7] = 0.0f;
    }
}

// K1: per-bucket: counting-sort bucket by local row (40 bins) in LDS, write
// back sorted + per-node segments {start,cnt}; deg -> dinv; g1 = dinv*h1.
__global__ __launch_bounds__(512) void k_sort_deg_g1(
    const int* __restrict__ gcur, int2* __restrict__ gbuf,
    const float* __restrict__ h1, float* __restrict__ dinv,
    float* __restrict__ g1, int2* __restrict__ nseg)
{
    __shared__ int   lhist[RN];
    __shared__ float ldeg[RN];
    __shared__ int   loffs[RN];
    __shared__ int   lcur[RN];
    __shared__ float ldv[RN];
    __shared__ int2  st[CAP];           // 24 KB
    const int tid = threadIdx.x, b = blockIdx.x;
    if (tid < RN) { lhist[tid] = 0; ldeg[tid] = 0.0f; }
    __syncthreads();
    const int cnt = gcur[b];
    int2* bk = gbuf + (size_t)b * CAP;
    int2 ed[6];
    #pragma unroll
    for (int k = 0; k < 6; ++k) {
        const int i = tid + k * 512;
        ed[k] = make_int2(-1, 0);
        if (i < cnt) {
            ed[k] = bk[i];
            const int rl = (ed[k].x >> 14) & 63;
            atomicAdd(&lhist[rl], 1);
            atomicAdd(&ldeg[rl], __int_as_float(ed[k].y));
        }
    }
    __syncthreads();
    if (tid < 64) {                      // scan 40 bins (wave 0)
        int v = (tid < RN) ? lhist[tid] : 0;
        int s = v;
        #pragma unroll
        for (int off = 1; off < 64; off <<= 1) {
            const int t = __shfl_up(s, off);
            if (tid >= off) s += t;
        }
        if (tid < RN) { loffs[tid] = s - v; lcur[tid] = s - v; }
    } else if (tid >= 64 && tid < 64 + RN) {
        ldv[tid - 64] = rsqrtf(1.0f + ldeg[tid - 64]);
    }
    __syncthreads();
    #pragma unroll
    for (int k = 0; k < 6; ++k) {
        if (ed[k].x >= 0) {
            const int rl = (ed[k].x >> 14) & 63;
            const int pos = atomicAdd(&lcur[rl], 1);
            st[pos] = ed[k];
        }
    }
    __syncthreads();
    #pragma unroll
    for (int k = 0; k < 6; ++k) {
        const int i = tid + k * 512;
        if (i < cnt) bk[i] = st[i];
    }
    if (tid < RN) {
        dinv[b * RN + tid] = ldv[tid];
        nseg[b * RN + tid] = make_int2(loffs[tid], lhist[tid]);
    }
    if (tid < RN * HP) {
        const int n = tid >> 3;
        g1[(size_t)(b * RN) * HP + tid] = ldv[n] * h1[(size_t)(b * RN) * HP + tid];
    }
}

// K2: gather layer1 (+b1) + mm2 -> g2. One node per wave, no atomics.
__global__ __launch_bounds__(512) void k_gather1(
    const int2* __restrict__ gbuf, const int2* __restrict__ nseg,
    const float* __restrict__ dinv, const float* __restrict__ g1,
    const float* __restrict__ b1, const float* __restrict__ W2,
    float* __restrict__ g2)
{
    __shared__ float asum[NSPB][HP];
    __shared__ float vals[NSPB][HP];
    __shared__ float ldv[NSPB];
    __shared__ float w2[H * H];
    __shared__ float bb[H];
    const int tid = threadIdx.x, b = blockIdx.x;
    const int wv = tid >> 6, ln = tid & 63;
    if (tid < NSPB) ldv[tid] = dinv[b * NSPB + tid];
    if (tid >= 64 && tid < 64 + H * H) w2[tid - 64] = W2[tid - 64];
    if (tid >= 128 && tid < 128 + H) bb[tid - 128] = b1[tid - 128];
    __syncthreads();
    const int2* bk = gbuf + (size_t)(b / 2) * CAP;
    for (int n = wv; n < NSPB; n += 8) {
        const int2 seg = nseg[b * NSPB + n];
        float acc[H] = {};
        for (int k = seg.x + ln; k < seg.x + seg.y; k += 64) {
            const int2 e = bk[k];
            const float w = __int_as_float(e.y);
            const float4* gc = (const float4*)(g1 + (size_t)(e.x & 16383) * HP);
            const float4 lo = gc[0], hi = gc[1];
            acc[0] += w * lo.x; acc[1] += w * lo.y; acc[2] += w * lo.z;
            acc[3] += w * lo.w; acc[4] += w * hi.x; acc[5] += w * hi.y;
            acc[6] += w * hi.z;
        }
        #pragma unroll
        for (int j = 0; j < H; ++j) {
            const float s = wave_sum(acc[j]);
            if (ln == 0) asum[n][j] = s;
        }
    }
    __syncthreads();
    if (tid < NSPB * H) {
        const int n = tid / H, k = tid - n * H;
        const int gn = b * NSPB + n;
        vals[n][k] = ldv[n] * (asum[n][k] + g1[(size_t)gn * HP + k]) + bb[k];
    }
    __syncthreads();
    if (tid < NSPB * H) {
        const int n = tid / H, k = tid - n * H;
        const int gn = b * NSPB + n;
        float o = 0.0f;
        #pragma unroll
        for (int j = 0; j < H; ++j) o += vals[n][j] * w2[j * H + k];
        g2[(size_t)gn * HP + k] = ldv[n] * o;
    }
    if (tid >= 256 && tid < 256 + NSPB)
        g2[(size_t)(b * NSPB + tid - 256) * HP + 7] = 0.0f;
}

// K3: gather layer2 (+b2) -> dout (stride 7) + reg element.
__global__ __launch_bounds__(512) void k_gather2(
    const int2* __restrict__ gbuf, const int2* __restrict__ nseg,
    const float* __restrict__ dinv, const float* __restrict__ g2,
    const float* __restrict__ b2, float* __restrict__ dout)
{
    __shared__ float asum[NSPB][HP];
    __shared__ float ldv[NSPB];
    __shared__ float bb[H];
    const int tid = threadIdx.x, b = blockIdx.x;
    const int wv = tid >> 6, ln = tid & 63;
    if (b == 0 && tid == 511) dout[(size_t)NN * H] = 0.0f;   // reg
    if (tid < NSPB) ldv[tid] = dinv[b * NSPB + tid];
    if (tid >= 128 && tid < 128 + H) bb[tid - 128] = b2[tid - 128];
    __syncthreads();
    const int2* bk = gbuf + (size_t)(b / 2) * CAP;
    for (int n = wv; n < NSPB; n += 8) {
        const int2 seg = nseg[b * NSPB + n];
        float acc[H] = {};
        for (int k = seg.x + ln; k < seg.x + seg.y; k += 64) {
            const int2 e = bk[k];
            const float w = __int_as_float(e.y);
            const float4* gc = (const float4*)(g2 + (size_t)(e.x & 16383) * HP);
            const float4 lo = gc[0], hi = gc[1];
            acc[0] += w * lo.x; acc[1] += w * lo.y; acc[2] += w * lo.z;
            acc[3] += w * lo.w; acc[4] += w * hi.x; acc[5] += w * hi.y;
            acc[6] += w * hi.z;
        }
        #pragma unroll
        for (int j = 0; j < H; ++j) {
            const float s = wave_sum(acc[j]);
            if (ln == 0) asum[n][j] = s;
        }
    }
    __syncthreads();
    if (tid < NSPB * H) {
        const int n = tid / H, k = tid - n * H;
        const int gn = b * NSPB + n;
        dout[(size_t)gn * H + k] =
            ldv[n] * (asum[n][k] + g2[(size_t)gn * HP + k]) + bb[k];
    }
}

extern "C" void kernel_launch(void* const* d_in, const int* in_sizes, int n_in,
                              void* d_out, int out_size, void* d_ws, size_t ws_size,
                              hipStream_t stream) {
    const float* x  = (const float*)d_in[0];
    const int*   ei = (const int*)d_in[1];
    const float* ea = (const float*)d_in[2];
    const float* W1 = (const float*)d_in[4];
    const float* b1 = (const float*)d_in[5];
    const float* W2 = (const float*)d_in[6];
    const float* b2 = (const float*)d_in[7];
    float* out = (float*)d_out;

    char* p = (char*)d_ws;
    int* gcur = (int*)p;          p += 1024;
    int2* gbuf = (int2*)p;        p += sizeof(int2) * RG * CAP;    // 6.1 MB
    int2* nseg = (int2*)p;        p += sizeof(int2) * NN;
    float* h1 = (float*)p;        p += sizeof(float) * NN * HP;
    float* g1 = (float*)p;        p += sizeof(float) * NN * HP;
    float* g2 = (float*)p;        p += sizeof(float) * NN * HP;
    float* dinv = (float*)p;      p += sizeof(float) * NN;

    const int* row = ei;
    const int* col = ei + NE;

    hipMemsetAsync(gcur, 0, RG * sizeof(int), stream);
    k_bucket_mm1<<<NCH + MMB, 1024, 0, stream>>>(row, col, ea, x, W1, gcur, gbuf, h1);
    k_sort_deg_g1<<<RG, 512, 0, stream>>>(gcur, gbuf, h1, dinv, g1, nseg);
    k_gather1<<<NGB, 512, 0, stream>>>(gbuf, nseg, dinv, g1, b1, W2, g2);
    k_gather2<<<NGB, 512, 0, stream>>>(gbuf, nseg, dinv, g2, b2, out);
}

// Round 13
// 54.973 us; speedup vs baseline: 2.8027x; 1.0855x over previous
//
#include <hip/hip_runtime.h>

#define NN   10000
#define NE   640000
#define IC   512
#define H    7
#define HP   8                     // padded h/g row stride (2x float4)
#define NCH  256                   // bucket chunks
#define CE   (NE / NCH)            // 2500 edges per chunk
#define RG   250                   // row ranges (buckets)
#define RN   40                    // nodes per range
#define CAP  3072                  // bucket capacity (mean 2560, max~2740)
#define MMB  256                   // mm1 blocks (40 rows each) -> K0 grid 512
#define GN   32                    // nodes per gather block (16-lane groups)
#define NGB  ((NN + GN - 1) / GN)  // 313 gather blocks

__device__ __forceinline__ float wave_sum(float v) {
    #pragma unroll
    for (int off = 32; off; off >>= 1) v += __shfl_xor(v, off);
    return v;
}

__device__ __forceinline__ float group16_sum(float v) {
    #pragma unroll
    for (int off = 1; off < 16; off <<= 1) v += __shfl_xor(v, off);
    return v;
}

// K0: blocks [0,NCH) bucket edges by row-range (LDS counting sort by rg,
// one global cursor atomic per range, coalesced write-out of
// {col | rl<<14 | rg<<20, ew}); blocks [NCH,NCH+MMB) compute mm1 (40 rows).
__global__ __launch_bounds__(1024) void k_bucket_mm1(
    const int* __restrict__ row, const int* __restrict__ col,
    const float* __restrict__ ew, const float* __restrict__ x,
    const float* __restrict__ W1, int* __restrict__ gcur,
    int2* __restrict__ gbuf, float* __restrict__ h1)
{
    __shared__ int   lhist[RG];
    __shared__ int   loffs[RG];
    __shared__ int   lbase[RG];
    __shared__ int   lcur[RG];
    __shared__ int2  st[CE];            // 20 KB
    __shared__ float wls[IC * H];       // 14 KB (mm1 branch)
    const int tid = threadIdx.x;

    if (blockIdx.x < NCH) {
        const int base = blockIdx.x * CE;
        if (tid < RG) lhist[tid] = 0;
        __syncthreads();
        int ex[3]; float ef[3];
        #pragma unroll
        for (int k = 0; k < 3; ++k) {
            const int i = tid + k * 1024;
            ex[k] = -1;
            if (i < CE) {
                const int e = base + i;
                const int r = row[e], c = col[e];
                const int rg = r / RN, rl = r - rg * RN;
                ex[k] = c | (rl << 14) | (rg << 20);
                ef[k] = ew[e];
                atomicAdd(&lhist[rg], 1);
            }
        }
        __syncthreads();
        if (tid < RG) lbase[tid] = tid * CAP + atomicAdd(&gcur[tid], lhist[tid]);
        if (tid < 64) {                  // exclusive scan of lhist (wave 0)
            const int ln = tid;
            int t4[4]; int s4 = 0;
            #pragma unroll
            for (int k = 0; k < 4; ++k) {
                const int j = ln * 4 + k;
                t4[k] = (j < RG) ? lhist[j] : 0;
                s4 += t4[k];
            }
            int s = s4;
            #pragma unroll
            for (int off = 1; off < 64; off <<= 1) {
                const int t = __shfl_up(s, off);
                if (ln >= off) s += t;
            }
            int run = s - s4;
            #pragma unroll
            for (int k = 0; k < 4; ++k) {
                const int j = ln * 4 + k;
                if (j < RG) { loffs[j] = run; lcur[j] = run; }
                run += t4[k];
            }
        }
        __syncthreads();
        #pragma unroll
        for (int k = 0; k < 3; ++k) {
            if (ex[k] >= 0) {
                const int pos = atomicAdd(&lcur[ex[k] >> 20], 1);
                st[pos] = make_int2(ex[k], __float_as_int(ef[k]));
            }
        }
        __syncthreads();
        #pragma unroll
        for (int k = 0; k < 3; ++k) {
            const int i = tid + k * 1024;
            if (i < CE) {
                const int rg = st[i].x >> 20;
                gbuf[lbase[rg] + (i - loffs[rg])] = st[i];
            }
        }
    } else {
        for (int i = tid; i < IC * H; i += 1024) wls[i] = W1[i];
        __syncthreads();
        const int wv = tid >> 6, ln = tid & 63;
        const int rb = (blockIdx.x - NCH) * RN;
        for (int r0 = wv; r0 < RN; r0 += 16) {          // 40 rows, 16 waves
            const int r = rb + r0;
            const float4* xr4 = (const float4*)(x + (size_t)r * IC);
            const float4 a0 = xr4[ln * 2], a1 = xr4[ln * 2 + 1];
            const float e8[8] = {a0.x, a0.y, a0.z, a0.w, a1.x, a1.y, a1.z, a1.w};
            const float* wb = &wls[ln * 8 * H];
            float acc[H] = {};
            #pragma unroll
            for (int m = 0; m < 8; ++m)
                #pragma unroll
                for (int c = 0; c < H; ++c) acc[c] += e8[m] * wb[m * H + c];
            #pragma unroll
            for (int c = 0; c < H; ++c) {
                const float v = wave_sum(acc[c]);
                if (ln == 0) h1[r * HP + c] = v;
            }
            if (ln == 0) h1[r * HP + 7] = 0.0f;
        }
    }
}

// K1: per-bucket: counting-sort by local row (40 bins) in LDS, write back
// sorted + per-node segments {start,cnt}; deg -> dinv; g1 = dinv*h1.
__global__ __launch_bounds__(1024) void k_sort_deg_g1(
    const int* __restrict__ gcur, int2* __restrict__ gbuf,
    const float* __restrict__ h1, float* __restrict__ dinv,
    float* __restrict__ g1, int2* __restrict__ nseg)
{
    __shared__ int   lhist[RN];
    __shared__ float ldeg[RN];
    __shared__ int   loffs[RN];
    __shared__ int   lcur[RN];
    __shared__ float ldv[RN];
    __shared__ int2  st[CAP];           // 24 KB
    const int tid = threadIdx.x, b = blockIdx.x;
    if (tid < RN) { lhist[tid] = 0; ldeg[tid] = 0.0f; }
    __syncthreads();
    const int cnt = gcur[b];
    int2* bk = gbuf + (size_t)b * CAP;
    int2 ed[3];
    #pragma unroll
    for (int k = 0; k < 3; ++k) {
        const int i = tid + k * 1024;
        ed[k] = make_int2(-1, 0);
        if (i < cnt) {
            ed[k] = bk[i];
            const int rl = (ed[k].x >> 14) & 63;
            atomicAdd(&lhist[rl], 1);
            atomicAdd(&ldeg[rl], __int_as_float(ed[k].y));
        }
    }
    __syncthreads();
    if (tid < 64) {                      // scan 40 bins (wave 0)
        int v = (tid < RN) ? lhist[tid] : 0;
        int s = v;
        #pragma unroll
        for (int off = 1; off < 64; off <<= 1) {
            const int t = __shfl_up(s, off);
            if (tid >= off) s += t;
        }
        if (tid < RN) { loffs[tid] = s - v; lcur[tid] = s - v; }
    } else if (tid >= 64 && tid < 64 + RN) {
        ldv[tid - 64] = rsqrtf(1.0f + ldeg[tid - 64]);
    }
    __syncthreads();
    #pragma unroll
    for (int k = 0; k < 3; ++k) {
        if (ed[k].x >= 0) {
            const int rl = (ed[k].x >> 14) & 63;
            const int pos = atomicAdd(&lcur[rl], 1);
            st[pos] = ed[k];
        }
    }
    __syncthreads();
    #pragma unroll
    for (int k = 0; k < 3; ++k) {
        const int i = tid + k * 1024;
        if (i < cnt) bk[i] = st[i];
    }
    if (tid < RN) {
        dinv[b * RN + tid] = ldv[tid];
        nseg[b * RN + tid] = make_int2(loffs[tid], lhist[tid]);
    }
    if (tid < RN * HP) {
        const int n = tid >> 3;
        g1[(size_t)(b * RN) * HP + tid] = ldv[n] * h1[(size_t)(b * RN) * HP + tid];
    }
}

// K2/K3: gather, one node per 16-lane group (32 nodes/block, no atomics).
// Manual x2 unroll with masked tail keeps 2 g-row loads in flight.
template <bool FUSE_MM2>
__global__ __launch_bounds__(512) void k_gather(
    const int* __restrict__ gcur_unused, const int2* __restrict__ gbuf,
    const int2* __restrict__ nseg, const float* __restrict__ dinv,
    const float* __restrict__ g, const float* __restrict__ bias,
    const float* __restrict__ W2, float* __restrict__ out)
{
    __shared__ float asum[GN][HP];
    __shared__ float vals[GN][HP];
    __shared__ float ldv[GN];
    __shared__ float w2[H * H];
    __shared__ float bb[H];
    const int tid = threadIdx.x, b = blockIdx.x;
    const int gid = tid >> 4, q = tid & 15;             // 32 groups x 16 lanes
    const int gn = b * GN + gid;
    if (!FUSE_MM2 && b == 0 && tid == 511) out[(size_t)NN * H] = 0.0f;  // reg
    if (tid < GN && b * GN + tid < NN) ldv[tid] = dinv[b * GN + tid];
    if (FUSE_MM2 && tid >= 64 && tid < 64 + H * H) w2[tid - 64] = W2[tid - 64];
    if (tid >= 128 && tid < 128 + H) bb[tid - 128] = bias[tid - 128];
    __syncthreads();
    if (gn < NN) {
        const int2 seg = nseg[gn];
        const int2* bk = gbuf + (size_t)(gn / RN) * CAP;
        const int kend = seg.x + seg.y;
        float acc[H] = {};
        for (int k = seg.x + q; k < kend; k += 32) {
            const int k2i = k + 16;
            const int2 e0 = bk[k];
            const int2 e1 = bk[k2i < kend ? k2i : k];
            const float w0 = __int_as_float(e0.y);
            const float w1 = (k2i < kend) ? __int_as_float(e1.y) : 0.0f;
            const float4* p0 = (const float4*)(g + (size_t)(e0.x & 16383) * HP);
            const float4* p1 = (const float4*)(g + (size_t)(e1.x & 16383) * HP);
            const float4 lo0 = p0[0], hi0 = p0[1];
            const float4 lo1 = p1[0], hi1 = p1[1];
            acc[0] += w0 * lo0.x + w1 * lo1.x;
            acc[1] += w0 * lo0.y + w1 * lo1.y;
            acc[2] += w0 * lo0.z + w1 * lo1.z;
            acc[3] += w0 * lo0.w + w1 * lo1.w;
            acc[4] += w0 * hi0.x + w1 * hi1.x;
            acc[5] += w0 * hi0.y + w1 * hi1.y;
            acc[6] += w0 * hi0.z + w1 * hi1.z;
        }
        #pragma unroll
        for (int j = 0; j < H; ++j) {
            const float s = group16_sum(acc[j]);
            if (q == 0) asum[gid][j] = s;
        }
    }
    __syncthreads();
    if (tid < GN * H) {
        const int n = tid / H, k = tid - n * H;
        const int node = b * GN + n;
        if (node < NN)
            vals[n][k] = ldv[n] * (asum[n][k] + g[(size_t)node * HP + k]) + bb[k];
    }
    __syncthreads();
    if (tid < GN * H) {
        const int n = tid / H, k = tid - n * H;
        const int node = b * GN + n;
        if (node < NN) {
            if (FUSE_MM2) {
                float o = 0.0f;
                #pragma unroll
                for (int j = 0; j < H; ++j) o += vals[n][j] * w2[j * H + k];
                out[(size_t)node * HP + k] = ldv[n] * o;   // g2 = dinv*(v@W2)
            } else {
                out[(size_t)node * H + k] = vals[n][k];    // final, stride 7
            }
        }
    }
    if (FUSE_MM2 && tid >= 256 && tid < 256 + GN) {
        const int node = b * GN + (tid - 256);
        if (node < NN) out[(size_t)node * HP + 7] = 0.0f;
    }
}

extern "C" void kernel_launch(void* const* d_in, const int* in_sizes, int n_in,
                              void* d_out, int out_size, void* d_ws, size_t ws_size,
                              hipStream_t stream) {
    const float* x  = (const float*)d_in[0];
    const int*   ei = (const int*)d_in[1];
    const float* ea = (const float*)d_in[2];
    const float* W1 = (const float*)d_in[4];
    const float* b1 = (const float*)d_in[5];
    const float* W2 = (const float*)d_in[6];
    const float* b2 = (const float*)d_in[7];
    float* out = (float*)d_out;

    char* p = (char*)d_ws;
    int* gcur = (int*)p;          p += 1024;
    int2* gbuf = (int2*)p;        p += sizeof(int2) * RG * CAP;    // 6.1 MB
    int2* nseg = (int2*)p;        p += sizeof(int2) * NN;
    float* h1 = (float*)p;        p += sizeof(float) * NN * HP;
    float* g1 = (float*)p;        p += sizeof(float) * NN * HP;
    float* g2 = (float*)p;        p += sizeof(float) * NN * HP;
    float* dinv = (float*)p;      p += sizeof(float) * NN;

    const int* row = ei;
    const int* col = ei + NE;

    hipMemsetAsync(gcur, 0, RG * sizeof(int), stream);
    k_bucket_mm1<<<NCH + MMB, 1024, 0, stream>>>(row, col, ea, x, W1, gcur, gbuf, h1);
    k_sort_deg_g1<<<RG, 1024, 0, stream>>>(gcur, gbuf, h1, dinv, g1, nseg);
    k_gather<true><<<NGB, 512, 0, stream>>>(gcur, gbuf, nseg, dinv, g1, b1, W2, g2);
    k_gather<false><<<NGB, 512, 0, stream>>>(gcur, gbuf, nseg, dinv, g2, b2, nullptr, out);
}

// Round 14
// 47.845 us; speedup vs baseline: 3.2202x; 1.1490x over previous
//
#include <hip/hip_runtime.h>

#define NN   10000
#define NE   640000
#define IC   512
#define H    7
#define HP   8                     // padded h/g row stride (2x float4)
#define NCH  256                   // bucket chunks
#define CE   (NE / NCH)            // 2500 edges per chunk
#define RG   250                   // row ranges (buckets)
#define RN   40                    // nodes per range
#define CAP  3072                  // bucket capacity (mean 2560, 10 sigma)
#define MMB  256                   // mm1 blocks (40 rows each) -> K0 grid 512
#define GN   32                    // nodes per gather block (16-lane groups)
#define NGB  ((NN + GN - 1) / GN)  // 313 gather blocks

__device__ __forceinline__ float wave_sum(float v) {
    #pragma unroll
    for (int off = 32; off; off >>= 1) v += __shfl_xor(v, off);
    return v;
}

__device__ __forceinline__ float group16_sum(float v) {
    #pragma unroll
    for (int off = 1; off < 16; off <<= 1) v += __shfl_xor(v, off);
    return v;
}

// K0: blocks [0,NCH): sort own 2500-edge chunk by row-range in LDS, write it
// to the FIXED slot gbuf2[chunk*CE] (coalesced, no atomics, no reservation),
// plus per-chunk {count, offset} tables. Blocks [NCH,512): mm1 (40 rows each).
__global__ __launch_bounds__(1024) void k_bucket_mm1(
    const int* __restrict__ row, const int* __restrict__ col,
    const float* __restrict__ ew, const float* __restrict__ x,
    const float* __restrict__ W1, int* __restrict__ ghist,
    int* __restrict__ goffs, int2* __restrict__ gbuf2,
    float* __restrict__ h1)
{
    __shared__ int   lhist[RG];
    __shared__ int   loffs[RG];
    __shared__ int   lcur[RG];
    __shared__ int2  st[CE];            // 20 KB
    __shared__ float wls[IC * H];       // 14 KB (mm1 branch)
    const int tid = threadIdx.x;

    if (blockIdx.x < NCH) {
        const int base = blockIdx.x * CE;
        if (tid < RG) lhist[tid] = 0;
        __syncthreads();
        int ex[3]; float ef[3];
        #pragma unroll
        for (int k = 0; k < 3; ++k) {
            const int i = tid + k * 1024;
            ex[k] = -1;
            if (i < CE) {
                const int e = base + i;
                const int r = row[e], c = col[e];
                const int rg = r / RN, rl = r - rg * RN;
                ex[k] = c | (rl << 14) | (rg << 20);
                ef[k] = ew[e];
                atomicAdd(&lhist[rg], 1);          // LDS
            }
        }
        __syncthreads();
        if (tid < 64) {                  // exclusive scan of 250 counts (wave 0)
            const int ln = tid;
            int t4[4]; int s4 = 0;
            #pragma unroll
            for (int k = 0; k < 4; ++k) {
                const int j = ln * 4 + k;
                t4[k] = (j < RG) ? lhist[j] : 0;
                s4 += t4[k];
            }
            int s = s4;
            #pragma unroll
            for (int off = 1; off < 64; off <<= 1) {
                const int t = __shfl_up(s, off);
                if (ln >= off) s += t;
            }
            int run = s - s4;
            #pragma unroll
            for (int k = 0; k < 4; ++k) {
                const int j = ln * 4 + k;
                if (j < RG) { loffs[j] = run; lcur[j] = run; }
                run += t4[k];
            }
        }
        __syncthreads();
        #pragma unroll
        for (int k = 0; k < 3; ++k) {
            if (ex[k] >= 0) {
                const int pos = atomicAdd(&lcur[ex[k] >> 20], 1);   // LDS
                st[pos] = make_int2(ex[k], __float_as_int(ef[k]));
            }
        }
        __syncthreads();
        #pragma unroll
        for (int k = 0; k < 3; ++k) {       // coalesced write-out, fixed slot
            const int i = tid + k * 1024;
            if (i < CE) gbuf2[base + i] = st[i];
        }
        if (tid < RG) {
            ghist[blockIdx.x * RG + tid] = lhist[tid];
            goffs[blockIdx.x * RG + tid] = loffs[tid];
        }
    } else {
        for (int i = tid; i < IC * H; i += 1024) wls[i] = W1[i];
        __syncthreads();
        const int wv = tid >> 6, ln = tid & 63;
        const int rb = (blockIdx.x - NCH) * RN;
        for (int r0 = wv; r0 < RN; r0 += 16) {          // 40 rows, 16 waves
            const int r = rb + r0;
            if (r >= NN) break;
            const float4* xr4 = (const float4*)(x + (size_t)r * IC);
            const float4 a0 = xr4[ln * 2], a1 = xr4[ln * 2 + 1];
            const float e8[8] = {a0.x, a0.y, a0.z, a0.w, a1.x, a1.y, a1.z, a1.w};
            const float* wb = &wls[ln * 8 * H];
            float acc[H] = {};
            #pragma unroll
            for (int m = 0; m < 8; ++m)
                #pragma unroll
                for (int c = 0; c < H; ++c) acc[c] += e8[m] * wb[m * H + c];
            #pragma unroll
            for (int c = 0; c < H; ++c) {
                const float v = wave_sum(acc[c]);
                if (ln == 0) h1[r * HP + c] = v;
            }
            if (ln == 0) h1[r * HP + 7] = 0.0f;
        }
    }
}

// K1: per range b: gather the 256 per-chunk segments into LDS (4 threads per
// chunk), counting-sort by local row (40 bins), write sorted bucket + nseg;
// deg -> dinv; g1 = dinv*h1. No global atomics anywhere.
__global__ __launch_bounds__(1024) void k_sort_deg_g1(
    const int* __restrict__ ghist, const int* __restrict__ goffs,
    const int2* __restrict__ gbuf2, const float* __restrict__ h1,
    float* __restrict__ dinv, float* __restrict__ g1,
    int2* __restrict__ nseg, int2* __restrict__ gbuf)
{
    __shared__ int2  staged[CAP];       // 24 KB chunk-grouped edges
    __shared__ int2  st2[CAP];          // 24 KB row-sorted edges
    __shared__ int   ccnt[NCH];
    __shared__ int   coff[NCH];
    __shared__ int   total_s;
    __shared__ int   lhist[RN];
    __shared__ float ldeg[RN];
    __shared__ int   loffs[RN];
    __shared__ int   lcur[RN];
    __shared__ float ldv[RN];
    const int tid = threadIdx.x, b = blockIdx.x;

    if (tid < NCH) ccnt[tid] = ghist[tid * RG + b];
    if (tid >= 256 && tid < 256 + RN) { lhist[tid - 256] = 0; ldeg[tid - 256] = 0.0f; }
    __syncthreads();
    if (tid < 64) {                      // exclusive scan of 256 counts (wave 0)
        const int ln = tid;
        int t4[4]; int s4 = 0;
        #pragma unroll
        for (int k = 0; k < 4; ++k) { t4[k] = ccnt[ln * 4 + k]; s4 += t4[k]; }
        int s = s4;
        #pragma unroll
        for (int off = 1; off < 64; off <<= 1) {
            const int t = __shfl_up(s, off);
            if (ln >= off) s += t;
        }
        int run = s - s4;
        #pragma unroll
        for (int k = 0; k < 4; ++k) { coff[ln * 4 + k] = run; run += t4[k]; }
        if (ln == 63) total_s = run;
    }
    __syncthreads();
    {   // copy segments: 4 threads per chunk
        const int c = tid >> 2;
        const int cn = ccnt[c], co = coff[c];
        const int src = c * CE + goffs[c * RG + b];
        for (int i = tid & 3; i < cn; i += 4) staged[co + i] = gbuf2[src + i];
    }
    __syncthreads();
    const int cnt = total_s;
    int2 ed[3];
    #pragma unroll
    for (int k = 0; k < 3; ++k) {        // count bins + degree
        const int i = tid + k * 1024;
        ed[k] = make_int2(-1, 0);
        if (i < cnt) {
            ed[k] = staged[i];
            const int rl = (ed[k].x >> 14) & 63;
            atomicAdd(&lhist[rl], 1);
            atomicAdd(&ldeg[rl], __int_as_float(ed[k].y));
        }
    }
    __syncthreads();
    if (tid < 64) {                      // scan 40 bins (wave 0)
        int v = (tid < RN) ? lhist[tid] : 0;
        int s = v;
        #pragma unroll
        for (int off = 1; off < 64; off <<= 1) {
            const int t = __shfl_up(s, off);
            if (tid >= off) s += t;
        }
        if (tid < RN) { loffs[tid] = s - v; lcur[tid] = s - v; }
    } else if (tid >= 64 && tid < 64 + RN) {
        ldv[tid - 64] = rsqrtf(1.0f + ldeg[tid - 64]);
    }
    __syncthreads();
    #pragma unroll
    for (int k = 0; k < 3; ++k) {
        if (ed[k].x >= 0) {
            const int rl = (ed[k].x >> 14) & 63;
            const int pos = atomicAdd(&lcur[rl], 1);   // LDS
            st2[pos] = ed[k];
        }
    }
    __syncthreads();
    #pragma unroll
    for (int k = 0; k < 3; ++k) {        // sorted bucket out (coalesced)
        const int i = tid + k * 1024;
        if (i < cnt) gbuf[(size_t)b * CAP + i] = st2[i];
    }
    if (tid < RN) {
        dinv[b * RN + tid] = ldv[tid];
        nseg[b * RN + tid] = make_int2(loffs[tid], lhist[tid]);
    }
    if (tid < RN * HP) {
        const int n = tid >> 3;
        g1[(size_t)(b * RN) * HP + tid] = ldv[n] * h1[(size_t)(b * RN) * HP + tid];
    }
}

// K2/K3: gather, one node per 16-lane group (32 nodes/block, no atomics).
template <bool FUSE_MM2>
__global__ __launch_bounds__(512) void k_gather(
    const int2* __restrict__ gbuf, const int2* __restrict__ nseg,
    const float* __restrict__ dinv, const float* __restrict__ g,
    const float* __restrict__ bias, const float* __restrict__ W2,
    float* __restrict__ out)
{
    __shared__ float asum[GN][HP];
    __shared__ float vals[GN][HP];
    __shared__ float ldv[GN];
    __shared__ float w2[H * H];
    __shared__ float bb[H];
    const int tid = threadIdx.x, b = blockIdx.x;
    const int gid = tid >> 4, q = tid & 15;             // 32 groups x 16 lanes
    const int gn = b * GN + gid;
    if (!FUSE_MM2 && b == 0 && tid == 511) out[(size_t)NN * H] = 0.0f;  // reg
    if (tid < GN && b * GN + tid < NN) ldv[tid] = dinv[b * GN + tid];
    if (FUSE_MM2 && tid >= 64 && tid < 64 + H * H) w2[tid - 64] = W2[tid - 64];
    if (tid >= 128 && tid < 128 + H) bb[tid - 128] = bias[tid - 128];
    __syncthreads();
    if (gn < NN) {
        const int2 seg = nseg[gn];
        const int2* bk = gbuf + (size_t)(gn / RN) * CAP;
        const int kend = seg.x + seg.y;
        float acc[H] = {};
        for (int k = seg.x + q; k < kend; k += 32) {
            const int k2i = k + 16;
            const int2 e0 = bk[k];
            const int2 e1 = bk[k2i < kend ? k2i : k];
            const float w0 = __int_as_float(e0.y);
            const float w1 = (k2i < kend) ? __int_as_float(e1.y) : 0.0f;
            const float4* p0 = (const float4*)(g + (size_t)(e0.x & 16383) * HP);
            const float4* p1 = (const float4*)(g + (size_t)(e1.x & 16383) * HP);
            const float4 lo0 = p0[0], hi0 = p0[1];
            const float4 lo1 = p1[0], hi1 = p1[1];
            acc[0] += w0 * lo0.x + w1 * lo1.x;
            acc[1] += w0 * lo0.y + w1 * lo1.y;
            acc[2] += w0 * lo0.z + w1 * lo1.z;
            acc[3] += w0 * lo0.w + w1 * lo1.w;
            acc[4] += w0 * hi0.x + w1 * hi1.x;
            acc[5] += w0 * hi0.y + w1 * hi1.y;
            acc[6] += w0 * hi0.z + w1 * hi1.z;
        }
        #pragma unroll
        for (int j = 0; j < H; ++j) {
            const float s = group16_sum(acc[j]);
            if (q == 0) asum[gid][j] = s;
        }
    }
    __syncthreads();
    if (tid < GN * H) {
        const int n = tid / H, k = tid - n * H;
        const int node = b * GN + n;
        if (node < NN)
            vals[n][k] = ldv[n] * (asum[n][k] + g[(size_t)node * HP + k]) + bb[k];
    }
    __syncthreads();
    if (tid < GN * H) {
        const int n = tid / H, k = tid - n * H;
        const int node = b * GN + n;
        if (node < NN) {
            if (FUSE_MM2) {
                float o = 0.0f;
                #pragma unroll
                for (int j = 0; j < H; ++j) o += vals[n][j] * w2[j * H + k];
                out[(size_t)node * HP + k] = ldv[n] * o;   // g2 = dinv*(v@W2)
            } else {
                out[(size_t)node * H + k] = vals[n][k];    // final, stride 7
            }
        }
    }
    if (FUSE_MM2 && tid >= 256 && tid < 256 + GN) {
        const int node = b * GN + (tid - 256);
        if (node < NN) out[(size_t)node * HP + 7] = 0.0f;
    }
}

extern "C" void kernel_launch(void* const* d_in, const int* in_sizes, int n_in,
                              void* d_out, int out_size, void* d_ws, size_t ws_size,
                              hipStream_t stream) {
    const float* x  = (const float*)d_in[0];
    const int*   ei = (const int*)d_in[1];
    const float* ea = (const float*)d_in[2];
    const float* W1 = (const float*)d_in[4];
    const float* b1 = (const float*)d_in[5];
    const float* W2 = (const float*)d_in[6];
    const float* b2 = (const float*)d_in[7];
    float* out = (float*)d_out;

    char* p = (char*)d_ws;
    int* ghist = (int*)p;         p += sizeof(int) * NCH * RG;     // 256 KB
    int* goffs = (int*)p;         p += sizeof(int) * NCH * RG;     // 256 KB
    int2* gbuf2 = (int2*)p;       p += sizeof(int2) * NE;          // 5.12 MB
    int2* gbuf = (int2*)p;        p += sizeof(int2) * RG * CAP;    // 6.14 MB
    int2* nseg = (int2*)p;        p += sizeof(int2) * NN;
    float* h1 = (float*)p;        p += sizeof(float) * NN * HP;
    float* g1 = (float*)p;        p += sizeof(float) * NN * HP;
    float* g2 = (float*)p;        p += sizeof(float) * NN * HP;
    float* dinv = (float*)p;      p += sizeof(float) * NN;

    const int* row = ei;
    const int* col = ei + NE;

    k_bucket_mm1<<<NCH + MMB, 1024, 0, stream>>>(row, col, ea, x, W1,
                                                 ghist, goffs, gbuf2, h1);
    k_sort_deg_g1<<<RG, 1024, 0, stream>>>(ghist, goffs, gbuf2, h1,
                                           dinv, g1, nseg, gbuf);
    k_gather<true><<<NGB, 512, 0, stream>>>(gbuf, nseg, dinv, g1, b1, W2, g2);
    k_gather<false><<<NGB, 512, 0, stream>>>(gbuf, nseg, dinv, g2, b2, nullptr, out);
}

// Round 15
// 45.011 us; speedup vs baseline: 3.4230x; 1.0630x over previous
//
#include <hip/hip_runtime.h>
#include <hip/hip_fp16.h>

#define NN   10000
#define NE   640000
#define IC   512
#define H    7
#define HP   8                     // padded g row stride (2x float4)
#define NCH  256                   // bucket chunks
#define CE   (NE / NCH)            // 2500 edges per chunk
#define RG   250                   // row ranges (buckets)
#define RN   40                    // nodes per range
#define CAP  3072                  // bucket capacity (mean 2560, +10 sigma)
#define GN   32                    // nodes per gather block (16-lane groups)
#define NGB  ((NN + GN - 1) / GN)  // 313 gather blocks

__device__ __forceinline__ float wave_sum(float v) {
    #pragma unroll
    for (int off = 32; off; off >>= 1) v += __shfl_xor(v, off);
    return v;
}

__device__ __forceinline__ float group16_sum(float v) {
    #pragma unroll
    for (int off = 1; off < 16; off <<= 1) v += __shfl_xor(v, off);
    return v;
}

// K0: pure bucket pass. Each block sorts its 2500-edge chunk by row-range in
// LDS and writes it to the FIXED slot gbuf2[chunk*CE] (coalesced, no global
// atomics), plus per-chunk {count, offset} tables.
__global__ __launch_bounds__(1024) void k_bucket(
    const int* __restrict__ row, const int* __restrict__ col,
    const float* __restrict__ ew, int* __restrict__ ghist,
    int* __restrict__ goffs, int2* __restrict__ gbuf2)
{
    __shared__ int   lhist[RG];
    __shared__ int   loffs[RG];
    __shared__ int   lcur[RG];
    __shared__ int2  st[CE];            // 20 KB
    const int tid = threadIdx.x;
    const int base = blockIdx.x * CE;
    if (tid < RG) lhist[tid] = 0;
    __syncthreads();
    int ex[3]; float ef[3];
    #pragma unroll
    for (int k = 0; k < 3; ++k) {
        const int i = tid + k * 1024;
        ex[k] = -1;
        if (i < CE) {
            const int e = base + i;
            const int r = row[e], c = col[e];
            const int rg = r / RN, rl = r - rg * RN;
            ex[k] = c | (rl << 14) | (rg << 20);
            ef[k] = ew[e];
            atomicAdd(&lhist[rg], 1);          // LDS
        }
    }
    __syncthreads();
    if (tid < 64) {                      // exclusive scan of 250 counts
        const int ln = tid;
        int t4[4]; int s4 = 0;
        #pragma unroll
        for (int k = 0; k < 4; ++k) {
            const int j = ln * 4 + k;
            t4[k] = (j < RG) ? lhist[j] : 0;
            s4 += t4[k];
        }
        int s = s4;
        #pragma unroll
        for (int off = 1; off < 64; off <<= 1) {
            const int t = __shfl_up(s, off);
            if (ln >= off) s += t;
        }
        int run = s - s4;
        #pragma unroll
        for (int k = 0; k < 4; ++k) {
            const int j = ln * 4 + k;
            if (j < RG) { loffs[j] = run; lcur[j] = run; }
            run += t4[k];
        }
    }
    __syncthreads();
    #pragma unroll
    for (int k = 0; k < 3; ++k) {
        if (ex[k] >= 0) {
            const int pos = atomicAdd(&lcur[ex[k] >> 20], 1);   // LDS
            st[pos] = make_int2(ex[k], __float_as_int(ef[k]));
        }
    }
    __syncthreads();
    #pragma unroll
    for (int k = 0; k < 3; ++k) {
        const int i = tid + k * 1024;
        if (i < CE) gbuf2[base + i] = st[i];
    }
    if (tid < RG) {
        ghist[blockIdx.x * RG + tid] = lhist[tid];
        goffs[blockIdx.x * RG + tid] = loffs[tid];
    }
}

// K1: per range b: stage the 256 per-chunk segments into LDS, mm1 (40 rows,
// overlaps the staging latency), deg -> dinv, in-place counting-sort by local
// row into packed 4B edges {col | fp16(ew)<<16}, write sorted bucket + nseg +
// g1 = dinv * h1. No global atomics.
__global__ __launch_bounds__(1024) void k_stage_sort_mm1(
    const int* __restrict__ ghist, const int* __restrict__ goffs,
    const int2* __restrict__ gbuf2, const float* __restrict__ x,
    const float* __restrict__ W1, float* __restrict__ dinv,
    float* __restrict__ g1, int2* __restrict__ nseg,
    unsigned int* __restrict__ gbuf)
{
    __shared__ int2  staged[CAP];       // 24 KB (reused as packed uint after)
    __shared__ float wls[IC * H];       // 14 KB
    __shared__ int   ccnt[NCH];
    __shared__ int   coff[NCH];
    __shared__ int   total_s;
    __shared__ int   lhist[RN];
    __shared__ float ldeg[RN];
    __shared__ int   loffs[RN];
    __shared__ int   lcur[RN];
    __shared__ float ldv[RN];
    __shared__ float htile[RN][HP];
    const int tid = threadIdx.x, b = blockIdx.x;
    const int wv = tid >> 6, ln = tid & 63;

    if (tid < NCH) ccnt[tid] = ghist[tid * RG + b];
    if (tid >= 256 && tid < 256 + RN) { lhist[tid - 256] = 0; ldeg[tid - 256] = 0.0f; }
    for (int i = tid; i < IC * H; i += 1024) wls[i] = W1[i];
    __syncthreads();
    if (tid < 64) {                      // exclusive scan of 256 chunk counts
        const int ln0 = tid;
        int t4[4]; int s4 = 0;
        #pragma unroll
        for (int k = 0; k < 4; ++k) { t4[k] = ccnt[ln0 * 4 + k]; s4 += t4[k]; }
        int s = s4;
        #pragma unroll
        for (int off = 1; off < 64; off <<= 1) {
            const int t = __shfl_up(s, off);
            if (ln0 >= off) s += t;
        }
        int run = s - s4;
        #pragma unroll
        for (int k = 0; k < 4; ++k) { coff[ln0 * 4 + k] = run; run += t4[k]; }
        if (ln0 == 63) total_s = run;
    }
    __syncthreads();
    {   // stage segments: 4 threads per chunk (scattered ~80B reads)
        const int c = tid >> 2;
        const int cn = ccnt[c], co = coff[c];
        const int src = c * CE + goffs[c * RG + b];
        for (int i = tid & 3; i < cn; i += 4) staged[co + i] = gbuf2[src + i];
    }
    {   // mm1: 40 rows over 16 waves — FMA work overlaps staging stalls
        for (int r0 = wv; r0 < RN; r0 += 16) {
            const int r = b * RN + r0;
            const float4* xr4 = (const float4*)(x + (size_t)r * IC);
            const float4 a0 = xr4[ln * 2], a1 = xr4[ln * 2 + 1];
            const float e8[8] = {a0.x, a0.y, a0.z, a0.w, a1.x, a1.y, a1.z, a1.w};
            const float* wb = &wls[ln * 8 * H];
            float acc[H] = {};
            #pragma unroll
            for (int m = 0; m < 8; ++m)
                #pragma unroll
                for (int c2 = 0; c2 < H; ++c2) acc[c2] += e8[m] * wb[m * H + c2];
            #pragma unroll
            for (int c2 = 0; c2 < H; ++c2) {
                const float v = wave_sum(acc[c2]);
                if (ln == 0) htile[r0][c2] = v;
            }
            if (ln == 0) htile[r0][7] = 0.0f;
        }
    }
    __syncthreads();
    const int cnt = total_s;
    int2 ed[3];
    #pragma unroll
    for (int k = 0; k < 3; ++k) {        // edges -> regs; bin counts + degree
        const int i = tid + k * 1024;
        ed[k] = make_int2(-1, 0);
        if (i < cnt) {
            ed[k] = staged[i];
            const int rl = (ed[k].x >> 14) & 63;
            atomicAdd(&lhist[rl], 1);
            atomicAdd(&ldeg[rl], __int_as_float(ed[k].y));
        }
    }
    __syncthreads();
    if (tid < 64) {                      // scan 40 bins
        int v = (tid < RN) ? lhist[tid] : 0;
        int s = v;
        #pragma unroll
        for (int off = 1; off < 64; off <<= 1) {
            const int t = __shfl_up(s, off);
            if (tid >= off) s += t;
        }
        if (tid < RN) { loffs[tid] = s - v; lcur[tid] = s - v; }
    } else if (tid >= 64 && tid < 64 + RN) {
        ldv[tid - 64] = rsqrtf(1.0f + ldeg[tid - 64]);
    }
    __syncthreads();
    unsigned int* stp = (unsigned int*)staged;   // in-place packed scatter
    #pragma unroll
    for (int k = 0; k < 3; ++k) {
        if (ed[k].x >= 0) {
            const int rl = (ed[k].x >> 14) & 63;
            const int pos = atomicAdd(&lcur[rl], 1);   // LDS
            const unsigned short wb16 =
                __half_as_ushort(__float2half_rn(__int_as_float(ed[k].y)));
            stp[pos] = (unsigned int)(ed[k].x & 16383) | ((unsigned int)wb16 << 16);
        }
    }
    __syncthreads();
    #pragma unroll
    for (int k = 0; k < 3; ++k) {        // packed sorted bucket out (coalesced)
        const int i = tid + k * 1024;
        if (i < cnt) gbuf[(size_t)b * CAP + i] = stp[i];
    }
    if (tid < RN) {
        dinv[b * RN + tid] = ldv[tid];
        nseg[b * RN + tid] = make_int2(loffs[tid], lhist[tid]);
    }
    if (tid < RN * HP) {
        const int n = tid >> 3;
        g1[(size_t)(b * RN) * HP + tid] = ldv[n] * htile[n][tid & 7];
    }
}

// K2/K3: gather, one node per 16-lane group (32 nodes/block, no atomics).
// Packed 4B edges: col = e & 16383, w = fp16 in bits 16-31.
template <bool FUSE_MM2>
__global__ __launch_bounds__(512) void k_gather(
    const unsigned int* __restrict__ gbuf, const int2* __restrict__ nseg,
    const float* __restrict__ dinv, const float* __restrict__ g,
    const float* __restrict__ bias, const float* __restrict__ W2,
    float* __restrict__ out)
{
    __shared__ float asum[GN][HP];
    __shared__ float vals[GN][HP];
    __shared__ float ldv[GN];
    __shared__ float w2[H * H];
    __shared__ float bb[H];
    const int tid = threadIdx.x, b = blockIdx.x;
    const int gid = tid >> 4, q = tid & 15;             // 32 groups x 16 lanes
    const int gn = b * GN + gid;
    if (!FUSE_MM2 && b == 0 && tid == 511) out[(size_t)NN * H] = 0.0f;  // reg
    if (tid < GN && b * GN + tid < NN) ldv[tid] = dinv[b * GN + tid];
    if (FUSE_MM2 && tid >= 64 && tid < 64 + H * H) w2[tid - 64] = W2[tid - 64];
    if (tid >= 128 && tid < 128 + H) bb[tid - 128] = bias[tid - 128];
    __syncthreads();
    if (gn < NN) {
        const int2 seg = nseg[gn];
        const unsigned int* bk = gbuf + (size_t)(gn / RN) * CAP;
        const int kend = seg.x + seg.y;
        float acc[H] = {};
        for (int k = seg.x + q; k < kend; k += 32) {
            const int k2i = k + 16;
            const unsigned int e0 = bk[k];
            const unsigned int e1 = bk[k2i < kend ? k2i : k];
            const float w0 = __half2float(__ushort_as_half((unsigned short)(e0 >> 16)));
            float w1 = __half2float(__ushort_as_half((unsigned short)(e1 >> 16)));
            if (k2i >= kend) w1 = 0.0f;
            const float4* p0 = (const float4*)(g + (size_t)(e0 & 16383u) * HP);
            const float4* p1 = (const float4*)(g + (size_t)(e1 & 16383u) * HP);
            const float4 lo0 = p0[0], hi0 = p0[1];
            const float4 lo1 = p1[0], hi1 = p1[1];
            acc[0] += w0 * lo0.x + w1 * lo1.x;
            acc[1] += w0 * lo0.y + w1 * lo1.y;
            acc[2] += w0 * lo0.z + w1 * lo1.z;
            acc[3] += w0 * lo0.w + w1 * lo1.w;
            acc[4] += w0 * hi0.x + w1 * hi1.x;
            acc[5] += w0 * hi0.y + w1 * hi1.y;
            acc[6] += w0 * hi0.z + w1 * hi1.z;
        }
        #pragma unroll
        for (int j = 0; j < H; ++j) {
            const float s = group16_sum(acc[j]);
            if (q == 0) asum[gid][j] = s;
        }
    }
    __syncthreads();
    if (tid < GN * H) {
        const int n = tid / H, k = tid - n * H;
        const int node = b * GN + n;
        if (node < NN)
            vals[n][k] = ldv[n] * (asum[n][k] + g[(size_t)node * HP + k]) + bb[k];
    }
    __syncthreads();
    if (tid < GN * H) {
        const int n = tid / H, k = tid - n * H;
        const int node = b * GN + n;
        if (node < NN) {
            if (FUSE_MM2) {
                float o = 0.0f;
                #pragma unroll
                for (int j = 0; j < H; ++j) o += vals[n][j] * w2[j * H + k];
                out[(size_t)node * HP + k] = ldv[n] * o;   // g2 = dinv*(v@W2)
            } else {
                out[(size_t)node * H + k] = vals[n][k];    // final, stride 7
            }
        }
    }
    if (FUSE_MM2 && tid >= 256 && tid < 256 + GN) {
        const int node = b * GN + (tid - 256);
        if (node < NN) out[(size_t)node * HP + 7] = 0.0f;
    }
}

extern "C" void kernel_launch(void* const* d_in, const int* in_sizes, int n_in,
                              void* d_out, int out_size, void* d_ws, size_t ws_size,
                              hipStream_t stream) {
    const float* x  = (const float*)d_in[0];
    const int*   ei = (const int*)d_in[1];
    const float* ea = (const float*)d_in[2];
    const float* W1 = (const float*)d_in[4];
    const float* b1 = (const float*)d_in[5];
    const float* W2 = (const float*)d_in[6];
    const float* b2 = (const float*)d_in[7];
    float* out = (float*)d_out;

    char* p = (char*)d_ws;
    int* ghist = (int*)p;                 p += sizeof(int) * NCH * RG;
    int* goffs = (int*)p;                 p += sizeof(int) * NCH * RG;
    int2* gbuf2 = (int2*)p;               p += sizeof(int2) * NE;       // 5.12 MB
    unsigned int* gbuf = (unsigned int*)p; p += sizeof(unsigned int) * RG * CAP; // 3.07 MB
    int2* nseg = (int2*)p;                p += sizeof(int2) * NN;
    float* g1 = (float*)p;                p += sizeof(float) * NN * HP;
    float* g2 = (float*)p;                p += sizeof(float) * NN * HP;
    float* dinv = (float*)p;              p += sizeof(float) * NN;

    const int* row = ei;
    const int* col = ei + NE;

    k_bucket<<<NCH, 1024, 0, stream>>>(row, col, ea, ghist, goffs, gbuf2);
    k_stage_sort_mm1<<<RG, 1024, 0, stream>>>(ghist, goffs, gbuf2, x, W1,
                                              dinv, g1, nseg, gbuf);
    k_gather<true><<<NGB, 512, 0, stream>>>(gbuf, nseg, dinv, g1, b1, W2, g2);
    k_gather<false><<<NGB, 512, 0, stream>>>(gbuf, nseg, dinv, g2, b2, nullptr, out);
}